// Round 3
// baseline (1636.635 us; speedup 1.0000x reference)
//
#include <hip/hip_runtime.h>

#define DMv 384
#define DEv 64
#define NEB 4

typedef __attribute__((ext_vector_type(8))) __bf16 bf16x8;
typedef __attribute__((ext_vector_type(4))) float f32x4;

// ---------- bf16 helpers (raw ushort storage) ----------
__device__ __forceinline__ float bf_lo(unsigned u){ return __uint_as_float(u << 16); }
__device__ __forceinline__ float bf_hi(unsigned u){ return __uint_as_float(u & 0xffff0000u); }
__device__ __forceinline__ unsigned short f2bf(float f){
  unsigned u = __float_as_uint(f);
  unsigned r = (u + 0x7fffu + ((u >> 16) & 1u)) >> 16;
  return (unsigned short)r;
}
__device__ __forceinline__ float bf2f(unsigned short s){ return __uint_as_float(((unsigned)s) << 16); }

// ---------- atom embedding: hbf = bf16(lut[x] * sqrt(384)) ----------
__global__ void embed_k(const int* __restrict__ x, const float* __restrict__ lut,
                        unsigned short* __restrict__ hbf) {
  int n = blockIdx.x, c = threadIdx.x;
  hbf[(size_t)n*DMv + c] = f2bf(lut[(size_t)x[n]*DMv + c] * 19.595917942265423f);
}

// ---------- W2 = We0 @ We  (f32 [2][48][384], rows 41..47 zero), bias2 = be0 @ We ----------
__global__ void w2_k(const float* __restrict__ We0, const float* __restrict__ be0,
                     const float* __restrict__ We, float* __restrict__ W2,
                     float* __restrict__ bias2) {
  int k = blockIdx.x;         // 0..48
  int l = blockIdx.y;
  int j = threadIdx.x;        // 0..383
  const float* Wel = We + (size_t)l*DEv*DMv;
  if (k == 48) {
    float s = 0.f;
    for (int c = 0; c < DEv; ++c) s = fmaf(be0[c], Wel[c*DMv + j], s);
    bias2[l*DMv + j] = s;
    return;
  }
  float s = 0.f;
  if (k < 41) {
    for (int c = 0; c < DEv; ++c) s = fmaf(We0[k*DEv + c], Wel[c*DMv + j], s);
  }
  W2[((size_t)l*48 + k)*DMv + j] = s;
}

// ---------- WcatT bf16 [2][1152][384]: rows = output col (Wl|Wr|Wres), contiguous K ----------
__global__ void wcat_k(const float* __restrict__ Wl, const float* __restrict__ Wr,
                       const float* __restrict__ Wres, unsigned short* __restrict__ WcatT) {
  int n = blockIdx.x;   // 0..1151
  int l = blockIdx.y;
  int k = threadIdx.x;  // 0..383
  const float* src;
  int nn;
  if (n < 384)      { src = Wl   + (size_t)l*DMv*DMv; nn = n; }
  else if (n < 768) { src = Wr   + (size_t)l*DMv*DMv; nn = n - 384; }
  else              { src = Wres + (size_t)l*DMv*DMv; nn = n - 768; }
  WcatT[((size_t)l*1152 + n)*DMv + k] = f2bf(src[(size_t)k*DMv + nn]);
}

// ---------- per-edge 8-value gaussian basis window (start mult of 4) ----------
__global__ void bas8_k(const float* __restrict__ edge_attr,
                       uint4* __restrict__ bas8, int* __restrict__ ofs, int Ecnt) {
  int e = blockIdx.x*256 + threadIdx.x;
  if (e >= Ecnt) return;
  float d = edge_attr[e];
  int kc = (int)(d*5.0f + 0.5f);
  int s = (kc - 2) & ~3;
  if (s < 0) s = 0;
  float v[8];
  #pragma unroll
  for (int i = 0; i < 8; ++i) {
    float df = (d - 0.2f*(float)(s+i)) * 5.0f;
    v[i] = __expf(-(df*df)) * (1.0f/1.12f);
  }
  uint4 u;
  u.x = (unsigned)f2bf(v[0]) | ((unsigned)f2bf(v[1]) << 16);
  u.y = (unsigned)f2bf(v[2]) | ((unsigned)f2bf(v[3]) << 16);
  u.z = (unsigned)f2bf(v[4]) | ((unsigned)f2bf(v[5]) << 16);
  u.w = (unsigned)f2bf(v[6]) | ((unsigned)f2bf(v[7]) << 16);
  bas8[e] = u;
  ofs[e] = s;
}

// ---------- CSR build ----------
__global__ void count_k(const int* __restrict__ tgt, int* __restrict__ cnt, int Ecnt) {
  int e = blockIdx.x*256 + threadIdx.x;
  if (e < Ecnt) atomicAdd(&cnt[tgt[e]], 1);
}
__global__ void scan1_k(const int* __restrict__ cnt, int* __restrict__ rowptr,
                        int* __restrict__ bsum, int n) {
  __shared__ int tmp[256];
  int tid = threadIdx.x, i = blockIdx.x*256 + tid;
  int v = (i < n) ? cnt[i] : 0;
  tmp[tid] = v; __syncthreads();
  for (int off = 1; off < 256; off <<= 1) {
    int xv = (tid >= off) ? tmp[tid-off] : 0;
    __syncthreads();
    tmp[tid] += xv;
    __syncthreads();
  }
  if (i < n) rowptr[i] = tmp[tid] - v;
  if (tid == 255) bsum[blockIdx.x] = tmp[255];
}
__global__ void scan2_k(const int* __restrict__ bsum, int* __restrict__ bsumx, int nb) {
  __shared__ int tmp[256];
  int tid = threadIdx.x;
  int v = (tid < nb) ? bsum[tid] : 0;
  tmp[tid] = v; __syncthreads();
  for (int off = 1; off < 256; off <<= 1) {
    int xv = (tid >= off) ? tmp[tid-off] : 0;
    __syncthreads();
    tmp[tid] += xv;
    __syncthreads();
  }
  bsumx[tid] = tmp[tid] - v;
}
__global__ void scan3_k(int* __restrict__ rowptr, const int* __restrict__ bsumx,
                        int n, int total) {
  int i = blockIdx.x*256 + threadIdx.x;
  if (i < n) rowptr[i] += bsumx[blockIdx.x];
  if (i == 0) rowptr[n] = total;
}
__global__ void fill_k(const int* __restrict__ tgt, const int* __restrict__ rowptr,
                       int* __restrict__ fill, int* __restrict__ eidx, int Ecnt) {
  int e = blockIdx.x*256 + threadIdx.x;
  if (e >= Ecnt) return;
  int t = tgt[e];
  int pos = rowptr[t] + atomicAdd(&fill[t], 1);
  eidx[pos] = e;
}

// ---------- per-node mean basis: mb[N][48] bf16 = mean over incident edges of bas8 ----------
__global__ void mb_k(const uint4* __restrict__ bas8, const int* __restrict__ ofs,
                     const int* __restrict__ rowptr, const int* __restrict__ eidx,
                     unsigned short* __restrict__ mbbf, int Nn) {
  __shared__ float mbS[4][48];
  int tid = threadIdx.x, lane = tid & 63, wv = tid >> 6;
  int t = blockIdx.x*4 + wv;
  if (t >= Nn) return;
  if (lane < 48) mbS[wv][lane] = 0.f;
  asm volatile("s_waitcnt lgkmcnt(0)" ::: "memory");
  int rp = rowptr[t], deg = rowptr[t+1] - rp;
  for (int base = 0; base < deg; base += 64) {
    int i = base + lane;
    if (i < deg) {
      int eid = eidx[rp + i];
      uint4 bu = bas8[eid];
      int s = ofs[eid];
      atomicAdd(&mbS[wv][s+0], bf_lo(bu.x));
      atomicAdd(&mbS[wv][s+1], bf_hi(bu.x));
      atomicAdd(&mbS[wv][s+2], bf_lo(bu.y));
      atomicAdd(&mbS[wv][s+3], bf_hi(bu.y));
      atomicAdd(&mbS[wv][s+4], bf_lo(bu.z));
      atomicAdd(&mbS[wv][s+5], bf_hi(bu.z));
      atomicAdd(&mbS[wv][s+6], bf_lo(bu.w));
      atomicAdd(&mbS[wv][s+7], bf_hi(bu.w));
    }
  }
  asm volatile("s_waitcnt lgkmcnt(0)" ::: "memory");
  if (lane < 48) {
    float v = (lane < 44 && deg > 0) ? mbS[wv][lane] / (float)deg : 0.f;
    mbbf[(size_t)t*48 + lane] = f2bf(v);
  }
}

// ---------- bf16 MFMA GEMM: [M x 384] @ [384 x 1152] -> xl | xr | hres (f32, +bias) ----------
__global__ __launch_bounds__(256) void mfma_cat_k(
    const unsigned short* __restrict__ Abf,     // hbf [M][384]
    const unsigned short* __restrict__ Bt,      // WcatT layer [1152][384]
    const float* __restrict__ b0, const float* __restrict__ b1, const float* __restrict__ b2,
    float* __restrict__ C0, float* __restrict__ C1, float* __restrict__ C2, int M) {
  __shared__ unsigned short lds[2*8192];        // As 16KB | Bs 16KB, st_16x32 swizzled
  unsigned short* As = lds;
  unsigned short* Bs = lds + 8192;
  int tid = threadIdx.x;
  int lane = tid & 63, wv = tid >> 6;
  int wr = wv >> 1, wc = wv & 1;
  int bn = blockIdx.x * 128;
  int bm = blockIdx.y * 128;
  int srow = tid >> 3;            // 0..31
  int scol = (tid & 7) * 8;       // bf16 element col in [0,64)
  f32x4 acc[4][4] = {};
  uint4 av[4], bv[4];
  #pragma unroll
  for (int c = 0; c < 4; ++c) {
    int gr = bm + c*32 + srow; if (gr >= M) gr = M - 1;
    av[c] = *(const uint4*)(Abf + (size_t)gr*DMv + scol);
    bv[c] = *(const uint4*)(Bt + (size_t)(bn + c*32 + srow)*DMv + scol);
  }
  #pragma unroll
  for (int kt = 0; kt < 6; ++kt) {
    __syncthreads();
    #pragma unroll
    for (int c = 0; c < 4; ++c) {
      int r = c*32 + srow;
      int byteA = r*128 + scol*2;
      byteA ^= ((byteA >> 9) & 1) << 5;
      *(uint4*)((char*)As + byteA) = av[c];
      *(uint4*)((char*)Bs + byteA) = bv[c];
    }
    __syncthreads();
    if (kt < 5) {
      int k0 = (kt+1) * 64;
      #pragma unroll
      for (int c = 0; c < 4; ++c) {
        int gr = bm + c*32 + srow; if (gr >= M) gr = M - 1;
        av[c] = *(const uint4*)(Abf + (size_t)gr*DMv + k0 + scol);
        bv[c] = *(const uint4*)(Bt + (size_t)(bn + c*32 + srow)*DMv + k0 + scol);
      }
    }
    #pragma unroll
    for (int ks = 0; ks < 2; ++ks) {
      bf16x8 af[4], bfv[4];
      #pragma unroll
      for (int m = 0; m < 4; ++m) {
        int r = wr*64 + m*16 + (lane & 15);
        int byte = r*128 + ks*64 + ((lane >> 4)*16);
        byte ^= ((byte >> 9) & 1) << 5;
        af[m] = *(const bf16x8*)((const char*)As + byte);
      }
      #pragma unroll
      for (int n = 0; n < 4; ++n) {
        int r = wc*64 + n*16 + (lane & 15);
        int byte = r*128 + ks*64 + ((lane >> 4)*16);
        byte ^= ((byte >> 9) & 1) << 5;
        bfv[n] = *(const bf16x8*)((const char*)Bs + byte);
      }
      #pragma unroll
      for (int m = 0; m < 4; ++m)
        #pragma unroll
        for (int n = 0; n < 4; ++n)
          acc[m][n] = __builtin_amdgcn_mfma_f32_16x16x32_bf16(af[m], bfv[n], acc[m][n], 0, 0, 0);
    }
  }
  int seg = bn / 384;
  float* C = (seg == 0) ? C0 : (seg == 1) ? C1 : C2;
  const float* bias = (seg == 0) ? b0 : (seg == 1) ? b1 : b2;
  int cbase = bn - seg*384;
  #pragma unroll
  for (int n = 0; n < 4; ++n) {
    int col = cbase + wc*64 + n*16 + (lane & 15);
    float bsv = bias[col];
    #pragma unroll
    for (int m = 0; m < 4; ++m) {
      int r0 = bm + wr*64 + m*16 + ((lane >> 4)*4);
      #pragma unroll
      for (int q = 0; q < 4; ++q) {
        int r = r0 + q;
        if (r < M) C[(size_t)r*DMv + col] = acc[m][n][q] + bsv;
      }
    }
  }
}

// ---------- fused GAT layer v3: row-major W2 LDS (conflict-free), in-kernel self-loop ----------
__global__ __launch_bounds__(256, 4) void fused_gat3_k(
    const float* __restrict__ xl, const float* __restrict__ xr,
    const float* __restrict__ hres,
    const uint4* __restrict__ bas8, const int* __restrict__ ofs,
    const int* __restrict__ rowptr, const int* __restrict__ eidx,
    const int* __restrict__ srcs,
    const float* __restrict__ W2f,              // layer's [48][384] f32 (rows 41..47 zero)
    const float* __restrict__ bias2_l,          // [384]
    const unsigned short* __restrict__ mbbf,    // [N][48] bf16 mean basis
    const float* __restrict__ att_l,
    const float* __restrict__ ln_g, const float* __restrict__ ln_b,
    unsigned short* __restrict__ hbf, int Nn) {
  __shared__ unsigned short W2R[48 * DMv];      // row-major [k][j] bf16, 36.9 KB
  __shared__ float basS[4][NEB][8];
  __shared__ int ofsS[4][NEB];
  int tid = threadIdx.x;
  for (int i = tid; i < 48*DMv; i += 256) W2R[i] = f2bf(W2f[i]);
  __syncthreads();
  int lane = tid & 63, wv = tid >> 6;
  int j0 = lane * 6;
  for (int rep = 0; rep < 2; ++rep) {
    int t = blockIdx.x*8 + rep*4 + wv;
    if (t >= Nn) continue;
    int rp = rowptr[t], deg = rowptr[t+1] - rp;
    float att_j[6], xr_t[6];
    #pragma unroll
    for (int jj = 0; jj < 6; ++jj) {
      att_j[jj] = att_l[j0 + jj];
      xr_t[jj]  = xr[(size_t)t*DMv + j0 + jj] + bias2_l[j0 + jj];
    }
    float Mh = -INFINITY, S = 0.f;
    float acc[6] = {0.f,0.f,0.f,0.f,0.f,0.f};
    for (int base = 0; base < deg; base += NEB) {
      int nb = deg - base; if (nb > NEB) nb = NEB;
      int src_v = t;
      if (lane < NEB) {
        int item = base + lane;
        int idx = (item < deg) ? item : (deg - 1);
        int eid = eidx[rp + idx];
        src_v = srcs[eid];
        uint4 bu = bas8[eid];
        float* bp = &basS[wv][lane][0];
        *(float4*)bp     = make_float4(bf_lo(bu.x), bf_hi(bu.x), bf_lo(bu.y), bf_hi(bu.y));
        *(float4*)(bp+4) = make_float4(bf_lo(bu.z), bf_hi(bu.z), bf_lo(bu.w), bf_hi(bu.w));
        ofsS[wv][lane] = ofs[eid];
      }
      int sA[NEB];
      #pragma unroll
      for (int s = 0; s < NEB; ++s) sA[s] = __shfl(src_v, s);
      float xls[NEB][6];
      #pragma unroll
      for (int s = 0; s < NEB; ++s) {
        const float* xp = xl + (size_t)sA[s]*DMv + j0;
        float2 a = *(const float2*)xp;
        float2 b = *(const float2*)(xp+2);
        float2 c = *(const float2*)(xp+4);
        xls[s][0]=a.x; xls[s][1]=a.y; xls[s][2]=b.x; xls[s][3]=b.y; xls[s][4]=c.x; xls[s][5]=c.y;
      }
      asm volatile("s_waitcnt lgkmcnt(0)" ::: "memory");
      #pragma unroll
      for (int s = 0; s < NEB; ++s) {
        int s_e = ofsS[wv][s];
        float4 bb0 = *(const float4*)&basS[wv][s][0];
        float4 bb1 = *(const float4*)&basS[wv][s][4];
        float bb[8] = {bb0.x, bb0.y, bb0.z, bb0.w, bb1.x, bb1.y, bb1.z, bb1.w};
        float m6[6];
        #pragma unroll
        for (int jj = 0; jj < 6; ++jj) m6[jj] = xls[s][jj] + xr_t[jj];
        const unsigned short* wrow = W2R + s_e*DMv + j0;
        #pragma unroll
        for (int k2 = 0; k2 < 8; ++k2) {
          const unsigned short* p = wrow + k2*DMv;
          uint2 wa = *(const uint2*)p;
          unsigned wb = *(const unsigned*)(p + 4);
          float b = bb[k2];
          m6[0] = fmaf(b, bf_lo(wa.x), m6[0]);
          m6[1] = fmaf(b, bf_hi(wa.x), m6[1]);
          m6[2] = fmaf(b, bf_lo(wa.y), m6[2]);
          m6[3] = fmaf(b, bf_hi(wa.y), m6[3]);
          m6[4] = fmaf(b, bf_lo(wb),   m6[4]);
          m6[5] = fmaf(b, bf_hi(wb),   m6[5]);
        }
        float part = 0.f;
        #pragma unroll
        for (int jj = 0; jj < 6; ++jj) {
          float vl = (m6[jj] > 0.f) ? m6[jj] : 0.2f*m6[jj];
          part = fmaf(vl, att_j[jj], part);
        }
        part += __shfl_xor(part, 1);
        part += __shfl_xor(part, 2);
        part += __shfl_xor(part, 4);
        if (s < nb) {
          float nm = fmaxf(Mh, part);
          float f = __expf(Mh - nm);
          float w = __expf(part - nm);
          S = S*f + w;
          #pragma unroll
          for (int jj = 0; jj < 6; ++jj) acc[jj] = fmaf(acc[jj], f, w * xls[s][jj]);
          Mh = nm;
        }
      }
    }
    // self-loop: eproj = mb @ W2 computed in-kernel from LDS W2R
    {
      const float* xp = xl + (size_t)t*DMv + j0;
      float2 a = *(const float2*)xp;
      float2 b = *(const float2*)(xp+2);
      float2 c = *(const float2*)(xp+4);
      float xlt[6] = {a.x, a.y, b.x, b.y, c.x, c.y};
      float m6[6];
      #pragma unroll
      for (int jj = 0; jj < 6; ++jj) m6[jj] = xlt[jj] + xr_t[jj];
      if (deg == 0) {
        #pragma unroll
        for (int jj = 0; jj < 6; ++jj) m6[jj] -= bias2_l[j0 + jj];
      }
      const uint4* mbp = (const uint4*)(mbbf + (size_t)t*48);
      #pragma unroll
      for (int w = 0; w < 6; ++w) {
        uint4 bu = mbp[w];
        float bb[8] = {bf_lo(bu.x), bf_hi(bu.x), bf_lo(bu.y), bf_hi(bu.y),
                       bf_lo(bu.z), bf_hi(bu.z), bf_lo(bu.w), bf_hi(bu.w)};
        const unsigned short* wrow = W2R + (w*8)*DMv + j0;
        #pragma unroll
        for (int k2 = 0; k2 < 8; ++k2) {
          const unsigned short* p = wrow + k2*DMv;
          uint2 wa = *(const uint2*)p;
          unsigned wb = *(const unsigned*)(p + 4);
          float bk = bb[k2];
          m6[0] = fmaf(bk, bf_lo(wa.x), m6[0]);
          m6[1] = fmaf(bk, bf_hi(wa.x), m6[1]);
          m6[2] = fmaf(bk, bf_lo(wa.y), m6[2]);
          m6[3] = fmaf(bk, bf_hi(wa.y), m6[3]);
          m6[4] = fmaf(bk, bf_lo(wb),   m6[4]);
          m6[5] = fmaf(bk, bf_hi(wb),   m6[5]);
        }
      }
      float part = 0.f;
      #pragma unroll
      for (int jj = 0; jj < 6; ++jj) {
        float vl = (m6[jj] > 0.f) ? m6[jj] : 0.2f*m6[jj];
        part = fmaf(vl, att_j[jj], part);
      }
      part += __shfl_xor(part, 1);
      part += __shfl_xor(part, 2);
      part += __shfl_xor(part, 4);
      float nm = fmaxf(Mh, part);
      float f = __expf(Mh - nm);
      float w = __expf(part - nm);
      S = S*f + w;
      #pragma unroll
      for (int jj = 0; jj < 6; ++jj) acc[jj] = fmaf(acc[jj], f, w * xlt[jj]);
      Mh = nm;
    }
    // finalize: normalize, residual, LayerNorm, write bf16
    float inv = 1.0f / (S + 1e-16f);
    const float* hrp = hres + (size_t)t*DMv + j0;
    float outv[6]; float s1 = 0.f, s2 = 0.f;
    #pragma unroll
    for (int jj = 0; jj < 6; ++jj) {
      float o = fmaf(acc[jj], inv, hrp[jj]);
      outv[jj] = o; s1 += o; s2 += o*o;
    }
    #pragma unroll
    for (int m = 1; m < 64; m <<= 1) {
      s1 += __shfl_xor(s1, m);
      s2 += __shfl_xor(s2, m);
    }
    float mu  = s1 * (1.0f/384.0f);
    float var = s2 * (1.0f/384.0f) - mu*mu;
    float rs  = rsqrtf(var + 1e-5f);
    float o0 = (outv[0]-mu)*rs*ln_g[j0+0] + ln_b[j0+0];
    float o1 = (outv[1]-mu)*rs*ln_g[j0+1] + ln_b[j0+1];
    float o2 = (outv[2]-mu)*rs*ln_g[j0+2] + ln_b[j0+2];
    float o3 = (outv[3]-mu)*rs*ln_g[j0+3] + ln_b[j0+3];
    float o4 = (outv[4]-mu)*rs*ln_g[j0+4] + ln_b[j0+4];
    float o5 = (outv[5]-mu)*rs*ln_g[j0+5] + ln_b[j0+5];
    unsigned* hp = (unsigned*)(hbf + (size_t)t*DMv + j0);
    hp[0] = (unsigned)f2bf(o0) | ((unsigned)f2bf(o1) << 16);
    hp[1] = (unsigned)f2bf(o2) | ((unsigned)f2bf(o3) << 16);
    hp[2] = (unsigned)f2bf(o4) | ((unsigned)f2bf(o5) << 16);
  }
}

// ---------- BatchNorm (training-mode batch stats) on bf16 h ----------
__global__ void bn_reduce_k(const unsigned short* __restrict__ hbf, float* __restrict__ sums, int Nn) {
  int c = threadIdx.x;
  float s = 0.f, s2 = 0.f;
  for (int r = blockIdx.x; r < Nn; r += gridDim.x) {
    float v = bf2f(hbf[(size_t)r*DMv + c]);
    s += v; s2 += v*v;
  }
  atomicAdd(&sums[c], s);
  atomicAdd(&sums[DMv + c], s2);
}
__global__ void bn_params_k(const float* __restrict__ sums,
                            const float* __restrict__ bn_g, const float* __restrict__ bn_b,
                            float* __restrict__ scsh, int Nn) {
  int c = threadIdx.x;
  float mu  = sums[c] / (float)Nn;
  float var = sums[DMv + c] / (float)Nn - mu*mu;
  float rs  = rsqrtf(var + 1e-5f);
  float sc  = bn_g[c] * rs;
  scsh[c] = sc;
  scsh[DMv + c] = bn_b[c] - mu*sc;
}
__global__ void bn_apply_k(const unsigned short* __restrict__ hbf, const float* __restrict__ scsh,
                           float* __restrict__ out) {
  int c = threadIdx.x; int n = blockIdx.x;
  size_t i = (size_t)n*DMv + c;
  out[i] = fmaf(bf2f(hbf[i]), scsh[c], scsh[DMv + c]);
}

extern "C" void kernel_launch(void* const* d_in, const int* in_sizes, int n_in,
                              void* d_out, int out_size, void* d_ws, size_t ws_size,
                              hipStream_t stream) {
  const int Nn   = in_sizes[0];
  const int Ecnt = in_sizes[2];
  const int*   x         = (const int*)d_in[0];
  const int*   eindex    = (const int*)d_in[1];
  const int*   srcs      = eindex;
  const int*   tgts      = eindex + Ecnt;
  const float* edge_attr = (const float*)d_in[2];
  const float* lut       = (const float*)d_in[3];
  const float* We0       = (const float*)d_in[4];
  const float* be0       = (const float*)d_in[5];
  const float* Wl        = (const float*)d_in[6];
  const float* bl_       = (const float*)d_in[7];
  const float* Wr        = (const float*)d_in[8];
  const float* br_       = (const float*)d_in[9];
  const float* We        = (const float*)d_in[10];
  const float* att       = (const float*)d_in[11];
  const float* Wres      = (const float*)d_in[12];
  const float* bias_g    = (const float*)d_in[13];
  const float* ln_g      = (const float*)d_in[14];
  const float* ln_b      = (const float*)d_in[15];
  const float* bn_g      = (const float*)d_in[16];
  const float* bn_b      = (const float*)d_in[17];

  char* ws = (char*)d_ws;
  size_t off = 0;
  auto alloc = [&](size_t b) { size_t o = off; off += (b + 255) & ~(size_t)255; return o; };
  unsigned short* hbf   = (unsigned short*)(ws + alloc((size_t)Nn*DMv*2));
  float* xlB   = (float*)(ws + alloc((size_t)Nn*DMv*4));
  float* xrB   = (float*)(ws + alloc((size_t)Nn*DMv*4));
  float* hresB = (float*)(ws + alloc((size_t)Nn*DMv*4));
  unsigned short* mbbf = (unsigned short*)(ws + alloc((size_t)Nn*48*2));
  uint4* bas8  = (uint4*)(ws + alloc((size_t)Ecnt*16));
  int* ofs     = (int*)(ws + alloc((size_t)Ecnt*4));
  float* W2    = (float*)(ws + alloc((size_t)2*48*DMv*4));
  float* bias2 = (float*)(ws + alloc((size_t)2*DMv*4));
  unsigned short* WcatT = (unsigned short*)(ws + alloc((size_t)2*1152*DMv*2));
  int* rowptr  = (int*)(ws + alloc((size_t)(Nn+1)*4));
  int* cnt     = (int*)(ws + alloc((size_t)Nn*4));
  int* fillA   = (int*)(ws + alloc((size_t)Nn*4));
  int* eidxA   = (int*)(ws + alloc((size_t)Ecnt*4));
  int* bsum    = (int*)(ws + alloc(1024));
  int* bsumx   = (int*)(ws + alloc(1024));
  float* bnsum = (float*)(ws + alloc(2*DMv*4));
  float* scsh  = (float*)(ws + alloc(2*DMv*4));

  hipMemsetAsync(cnt,   0, (size_t)Nn*4, stream);
  hipMemsetAsync(fillA, 0, (size_t)Nn*4, stream);
  hipMemsetAsync(bnsum, 0, 2*DMv*4, stream);

  embed_k<<<Nn, DMv, 0, stream>>>(x, lut, hbf);
  w2_k<<<dim3(49, 2), DMv, 0, stream>>>(We0, be0, We, W2, bias2);
  wcat_k<<<dim3(1152, 2), DMv, 0, stream>>>(Wl, Wr, Wres, WcatT);
  bas8_k<<<(Ecnt+255)/256, 256, 0, stream>>>(edge_attr, bas8, ofs, Ecnt);
  count_k<<<(Ecnt+255)/256, 256, 0, stream>>>(tgts, cnt, Ecnt);
  int nblk = (Nn + 255)/256;
  scan1_k<<<nblk, 256, 0, stream>>>(cnt, rowptr, bsum, Nn);
  scan2_k<<<1, 256, 0, stream>>>(bsum, bsumx, nblk);
  scan3_k<<<nblk, 256, 0, stream>>>(rowptr, bsumx, Nn, Ecnt);
  fill_k<<<(Ecnt+255)/256, 256, 0, stream>>>(tgts, rowptr, fillA, eidxA, Ecnt);
  mb_k<<<(Nn+3)/4, 256, 0, stream>>>(bas8, ofs, rowptr, eidxA, mbbf, Nn);

  for (int l = 0; l < 2; ++l) {
    mfma_cat_k<<<dim3(9, (Nn+127)/128), 256, 0, stream>>>(
        hbf, WcatT + (size_t)l*1152*DMv,
        bl_ + (size_t)l*DMv, br_ + (size_t)l*DMv, bias_g + (size_t)l*DMv,
        xlB, xrB, hresB, Nn);
    fused_gat3_k<<<(Nn+7)/8, 256, 0, stream>>>(
        xlB, xrB, hresB, bas8, ofs, rowptr, eidxA, srcs,
        W2 + (size_t)l*48*DMv, bias2 + (size_t)l*DMv, mbbf,
        att + (size_t)l*DMv, ln_g + (size_t)l*DMv, ln_b + (size_t)l*DMv,
        hbf, Nn);
  }
  bn_reduce_k<<<200, DMv, 0, stream>>>(hbf, bnsum, Nn);
  bn_params_k<<<1, DMv, 0, stream>>>(bnsum, bn_g, bn_b, scsh, Nn);
  bn_apply_k<<<Nn, DMv, 0, stream>>>(hbf, scsh, (float*)d_out);
}

// Round 5
// 995.917 us; speedup vs baseline: 1.6433x; 1.6433x over previous
//
#include <hip/hip_runtime.h>

#define DMv 384
#define DEv 64

typedef __attribute__((ext_vector_type(8))) __bf16 bf16x8;
typedef __attribute__((ext_vector_type(4))) float f32x4;

// ---------- bf16 helpers (raw ushort storage) ----------
__device__ __forceinline__ float bf_lo(unsigned u){ return __uint_as_float(u << 16); }
__device__ __forceinline__ float bf_hi(unsigned u){ return __uint_as_float(u & 0xffff0000u); }
__device__ __forceinline__ unsigned short f2bf(float f){
  unsigned u = __float_as_uint(f);
  unsigned r = (u + 0x7fffu + ((u >> 16) & 1u)) >> 16;
  return (unsigned short)r;
}
__device__ __forceinline__ float bf2f(unsigned short s){ return __uint_as_float(((unsigned)s) << 16); }

// ---------- atom embedding: hbf = bf16(lut[x] * sqrt(384)) ----------
__global__ void embed_k(const int* __restrict__ x, const float* __restrict__ lut,
                        unsigned short* __restrict__ hbf) {
  int n = blockIdx.x, c = threadIdx.x;
  hbf[(size_t)n*DMv + c] = f2bf(lut[(size_t)x[n]*DMv + c] * 19.595917942265423f);
}

// ---------- W2 = We0 @ We  (f32 [2][48][384], rows 41..47 zero), bias2 = be0 @ We ----------
__global__ void w2_k(const float* __restrict__ We0, const float* __restrict__ be0,
                     const float* __restrict__ We, float* __restrict__ W2,
                     float* __restrict__ bias2) {
  int k = blockIdx.x;         // 0..48
  int l = blockIdx.y;
  int j = threadIdx.x;        // 0..383
  const float* Wel = We + (size_t)l*DEv*DMv;
  if (k == 48) {
    float s = 0.f;
    for (int c = 0; c < DEv; ++c) s = fmaf(be0[c], Wel[c*DMv + j], s);
    bias2[l*DMv + j] = s;
    return;
  }
  float s = 0.f;
  if (k < 41) {
    for (int c = 0; c < DEv; ++c) s = fmaf(We0[k*DEv + c], Wel[c*DMv + j], s);
  }
  W2[((size_t)l*48 + k)*DMv + j] = s;
}

// ---------- WcatT bf16 [2][1152][384]: rows = output col (Wl|Wr|Wres), contiguous K ----------
__global__ void wcat_k(const float* __restrict__ Wl, const float* __restrict__ Wr,
                       const float* __restrict__ Wres, unsigned short* __restrict__ WcatT) {
  int n = blockIdx.x;   // 0..1151
  int l = blockIdx.y;
  int k = threadIdx.x;  // 0..383
  const float* src;
  int nn;
  if (n < 384)      { src = Wl   + (size_t)l*DMv*DMv; nn = n; }
  else if (n < 768) { src = Wr   + (size_t)l*DMv*DMv; nn = n - 384; }
  else              { src = Wres + (size_t)l*DMv*DMv; nn = n - 768; }
  WcatT[((size_t)l*1152 + n)*DMv + k] = f2bf(src[(size_t)k*DMv + nn]);
}

// ---------- per-edge 8-value gaussian basis window (start mult of 4) ----------
__global__ void bas8_k(const float* __restrict__ edge_attr,
                       uint4* __restrict__ bas8, int* __restrict__ ofs, int Ecnt) {
  int e = blockIdx.x*256 + threadIdx.x;
  if (e >= Ecnt) return;
  float d = edge_attr[e];
  int kc = (int)(d*5.0f + 0.5f);
  int s = (kc - 2) & ~3;
  if (s < 0) s = 0;
  float v[8];
  #pragma unroll
  for (int i = 0; i < 8; ++i) {
    float df = (d - 0.2f*(float)(s+i)) * 5.0f;
    v[i] = __expf(-(df*df)) * (1.0f/1.12f);
  }
  uint4 u;
  u.x = (unsigned)f2bf(v[0]) | ((unsigned)f2bf(v[1]) << 16);
  u.y = (unsigned)f2bf(v[2]) | ((unsigned)f2bf(v[3]) << 16);
  u.z = (unsigned)f2bf(v[4]) | ((unsigned)f2bf(v[5]) << 16);
  u.w = (unsigned)f2bf(v[6]) | ((unsigned)f2bf(v[7]) << 16);
  bas8[e] = u;
  ofs[e] = s;
}

// ---------- CSR build ----------
__global__ void count_k(const int* __restrict__ tgt, int* __restrict__ cnt, int Ecnt) {
  int e = blockIdx.x*256 + threadIdx.x;
  if (e < Ecnt) atomicAdd(&cnt[tgt[e]], 1);
}
__global__ void scan1_k(const int* __restrict__ cnt, int* __restrict__ rowptr,
                        int* __restrict__ bsum, int n) {
  __shared__ int tmp[256];
  int tid = threadIdx.x, i = blockIdx.x*256 + tid;
  int v = (i < n) ? cnt[i] : 0;
  tmp[tid] = v; __syncthreads();
  for (int off = 1; off < 256; off <<= 1) {
    int xv = (tid >= off) ? tmp[tid-off] : 0;
    __syncthreads();
    tmp[tid] += xv;
    __syncthreads();
  }
  if (i < n) rowptr[i] = tmp[tid] - v;
  if (tid == 255) bsum[blockIdx.x] = tmp[255];
}
__global__ void scan2_k(const int* __restrict__ bsum, int* __restrict__ bsumx, int nb) {
  __shared__ int tmp[256];
  int tid = threadIdx.x;
  int v = (tid < nb) ? bsum[tid] : 0;
  tmp[tid] = v; __syncthreads();
  for (int off = 1; off < 256; off <<= 1) {
    int xv = (tid >= off) ? tmp[tid-off] : 0;
    __syncthreads();
    tmp[tid] += xv;
    __syncthreads();
  }
  bsumx[tid] = tmp[tid] - v;
}
__global__ void scan3_k(int* __restrict__ rowptr, const int* __restrict__ bsumx,
                        int n, int total) {
  int i = blockIdx.x*256 + threadIdx.x;
  if (i < n) rowptr[i] += bsumx[blockIdx.x];
  if (i == 0) rowptr[n] = total;
}
// fill CSR slots with edge records (CSR-ordered copies for streaming access)
__global__ void fill_k(const int* __restrict__ srcs, const int* __restrict__ tgt,
                       const int* __restrict__ rowptr, int* __restrict__ fill,
                       const uint4* __restrict__ bas8, const int* __restrict__ ofs,
                       int* __restrict__ srcc, int* __restrict__ tgtc,
                       uint4* __restrict__ bas8c, int* __restrict__ ofsc, int Ecnt) {
  int e = blockIdx.x*256 + threadIdx.x;
  if (e >= Ecnt) return;
  int t = tgt[e];
  int pos = rowptr[t] + atomicAdd(&fill[t], 1);
  srcc[pos] = srcs[e];
  tgtc[pos] = t;
  ofsc[pos] = ofs[e];
  bas8c[pos] = bas8[e];
}

// ---------- per-node mean basis: mb[N][48] bf16 (CSR-contiguous reads) ----------
__global__ void mb_k(const uint4* __restrict__ bas8c, const int* __restrict__ ofsc,
                     const int* __restrict__ rowptr,
                     unsigned short* __restrict__ mbbf, int Nn) {
  __shared__ float mbS[4][48];
  int tid = threadIdx.x, lane = tid & 63, wv = tid >> 6;
  int t = blockIdx.x*4 + wv;
  if (t >= Nn) return;
  if (lane < 48) mbS[wv][lane] = 0.f;
  asm volatile("s_waitcnt lgkmcnt(0)" ::: "memory");
  int rp = rowptr[t], deg = rowptr[t+1] - rp;
  for (int base = 0; base < deg; base += 64) {
    int i = base + lane;
    if (i < deg) {
      uint4 bu = bas8c[rp + i];
      int s = ofsc[rp + i];
      atomicAdd(&mbS[wv][s+0], bf_lo(bu.x));
      atomicAdd(&mbS[wv][s+1], bf_hi(bu.x));
      atomicAdd(&mbS[wv][s+2], bf_lo(bu.y));
      atomicAdd(&mbS[wv][s+3], bf_hi(bu.y));
      atomicAdd(&mbS[wv][s+4], bf_lo(bu.z));
      atomicAdd(&mbS[wv][s+5], bf_hi(bu.z));
      atomicAdd(&mbS[wv][s+6], bf_lo(bu.w));
      atomicAdd(&mbS[wv][s+7], bf_hi(bu.w));
    }
  }
  asm volatile("s_waitcnt lgkmcnt(0)" ::: "memory");
  if (lane < 48) {
    float v = (lane < 44 && deg > 0) ? mbS[wv][lane] / (float)deg : 0.f;
    mbbf[(size_t)t*48 + lane] = f2bf(v);
  }
}

// ---------- bf16 MFMA GEMM: [M x 384] @ [384 x 1152] -> xl | xr | hres (f32, +bias) ----------
__global__ __launch_bounds__(256) void mfma_cat_k(
    const unsigned short* __restrict__ Abf,
    const unsigned short* __restrict__ Bt,
    const float* __restrict__ b0, const float* __restrict__ b1, const float* __restrict__ b2,
    float* __restrict__ C0, float* __restrict__ C1, float* __restrict__ C2, int M) {
  __shared__ unsigned short lds[2*8192];
  unsigned short* As = lds;
  unsigned short* Bs = lds + 8192;
  int tid = threadIdx.x;
  int lane = tid & 63, wv = tid >> 6;
  int wr = wv >> 1, wc = wv & 1;
  int bn = blockIdx.x * 128;
  int bm = blockIdx.y * 128;
  int srow = tid >> 3;
  int scol = (tid & 7) * 8;
  f32x4 acc[4][4] = {};
  uint4 av[4], bv[4];
  #pragma unroll
  for (int c = 0; c < 4; ++c) {
    int gr = bm + c*32 + srow; if (gr >= M) gr = M - 1;
    av[c] = *(const uint4*)(Abf + (size_t)gr*DMv + scol);
    bv[c] = *(const uint4*)(Bt + (size_t)(bn + c*32 + srow)*DMv + scol);
  }
  #pragma unroll
  for (int kt = 0; kt < 6; ++kt) {
    __syncthreads();
    #pragma unroll
    for (int c = 0; c < 4; ++c) {
      int r = c*32 + srow;
      int byteA = r*128 + scol*2;
      byteA ^= ((byteA >> 9) & 1) << 5;
      *(uint4*)((char*)As + byteA) = av[c];
      *(uint4*)((char*)Bs + byteA) = bv[c];
    }
    __syncthreads();
    if (kt < 5) {
      int k0 = (kt+1) * 64;
      #pragma unroll
      for (int c = 0; c < 4; ++c) {
        int gr = bm + c*32 + srow; if (gr >= M) gr = M - 1;
        av[c] = *(const uint4*)(Abf + (size_t)gr*DMv + k0 + scol);
        bv[c] = *(const uint4*)(Bt + (size_t)(bn + c*32 + srow)*DMv + k0 + scol);
      }
    }
    #pragma unroll
    for (int ks = 0; ks < 2; ++ks) {
      bf16x8 af[4], bfv[4];
      #pragma unroll
      for (int m = 0; m < 4; ++m) {
        int r = wr*64 + m*16 + (lane & 15);
        int byte = r*128 + ks*64 + ((lane >> 4)*16);
        byte ^= ((byte >> 9) & 1) << 5;
        af[m] = *(const bf16x8*)((const char*)As + byte);
      }
      #pragma unroll
      for (int n = 0; n < 4; ++n) {
        int r = wc*64 + n*16 + (lane & 15);
        int byte = r*128 + ks*64 + ((lane >> 4)*16);
        byte ^= ((byte >> 9) & 1) << 5;
        bfv[n] = *(const bf16x8*)((const char*)Bs + byte);
      }
      #pragma unroll
      for (int m = 0; m < 4; ++m)
        #pragma unroll
        for (int n = 0; n < 4; ++n)
          acc[m][n] = __builtin_amdgcn_mfma_f32_16x16x32_bf16(af[m], bfv[n], acc[m][n], 0, 0, 0);
    }
  }
  int seg = bn / 384;
  float* C = (seg == 0) ? C0 : (seg == 1) ? C1 : C2;
  const float* bias = (seg == 0) ? b0 : (seg == 1) ? b1 : b2;
  int cbase = bn - seg*384;
  #pragma unroll
  for (int n = 0; n < 4; ++n) {
    int col = cbase + wc*64 + n*16 + (lane & 15);
    float bsv = bias[col];
    #pragma unroll
    for (int m = 0; m < 4; ++m) {
      int r0 = bm + wr*64 + m*16 + ((lane >> 4)*4);
      #pragma unroll
      for (int q = 0; q < 4; ++q) {
        int r = r0 + q;
        if (r < M) C[(size_t)r*DMv + col] = acc[m][n][q] + bsv;
      }
    }
  }
}

// ---------- phase A: edge-parallel alpha.  8 edges/batch, 4 batches/wave. ----------
__global__ __launch_bounds__(256) void alpha_edge_k(
    const float* __restrict__ xl, const float* __restrict__ xr,
    const uint4* __restrict__ bas8c, const int* __restrict__ ofsc,
    const int* __restrict__ srcc, const int* __restrict__ tgtc,
    const float* __restrict__ W2f, const float* __restrict__ bias2_l,
    const float* __restrict__ att_l,
    float* __restrict__ alphaE, int Ecnt) {
  __shared__ unsigned short W2R[48 * DMv];   // [k][j] bf16, 36.9 KB
  __shared__ float basS[4][8][8];
  __shared__ int ofsS[4][8];
  int tid = threadIdx.x;
  for (int i = tid; i < 48*DMv; i += 256) W2R[i] = f2bf(W2f[i]);
  __syncthreads();
  int lane = tid & 63, wv = tid >> 6;
  int j0 = lane * 6;
  float att_j[6], b2[6];
  #pragma unroll
  for (int jj = 0; jj < 6; ++jj) {
    att_j[jj] = att_l[j0 + jj];
    b2[jj]    = bias2_l[j0 + jj];
  }
  int wgid = blockIdx.x*4 + wv;
  for (int it = 0; it < 4; ++it) {
    int base = wgid*32 + it*8;
    if (base >= Ecnt) break;
    asm volatile("s_waitcnt lgkmcnt(0)" ::: "memory");   // WAR: prev reads done
    int src_v = 0, tgt_v = 0;
    if (lane < 8) {
      int p = base + lane; if (p >= Ecnt) p = Ecnt - 1;
      src_v = srcc[p]; tgt_v = tgtc[p];
      uint4 bu = bas8c[p];
      float* bp = &basS[wv][lane][0];
      bp[0]=bf_lo(bu.x); bp[1]=bf_hi(bu.x); bp[2]=bf_lo(bu.y); bp[3]=bf_hi(bu.y);
      bp[4]=bf_lo(bu.z); bp[5]=bf_hi(bu.z); bp[6]=bf_lo(bu.w); bp[7]=bf_hi(bu.w);
      ofsS[wv][lane] = ofsc[p];
    }
    // gather xl[src]+xr[tgt] rows; 16 independent 3x8B loads
    float sx[8][6];
    #pragma unroll
    for (int s = 0; s < 8; ++s) {
      int sr = __shfl(src_v, s), tg = __shfl(tgt_v, s);
      const float* xp = xl + (size_t)sr*DMv + j0;
      const float* yp = xr + (size_t)tg*DMv + j0;
      float2 a0 = ((const float2*)xp)[0], a1 = ((const float2*)xp)[1], a2 = ((const float2*)xp)[2];
      float2 c0 = ((const float2*)yp)[0], c1 = ((const float2*)yp)[1], c2 = ((const float2*)yp)[2];
      sx[s][0]=a0.x+c0.x+b2[0]; sx[s][1]=a0.y+c0.y+b2[1];
      sx[s][2]=a1.x+c1.x+b2[2]; sx[s][3]=a1.y+c1.y+b2[3];
      sx[s][4]=a2.x+c2.x+b2[4]; sx[s][5]=a2.y+c2.y+b2[5];
    }
    asm volatile("s_waitcnt lgkmcnt(0)" ::: "memory");   // basS/ofsS visible
    float aout[8];
    #pragma unroll
    for (int s = 0; s < 8; ++s) {
      int s_e = ofsS[wv][s];
      float bb[8];
      #pragma unroll
      for (int k2 = 0; k2 < 8; ++k2) bb[k2] = basS[wv][s][k2];
      float m6[6];
      #pragma unroll
      for (int jj = 0; jj < 6; ++jj) m6[jj] = sx[s][jj];
      const unsigned short* wrow = W2R + s_e*DMv + j0;
      #pragma unroll
      for (int k2 = 0; k2 < 8; ++k2) {
        const unsigned short* p = wrow + k2*DMv;
        unsigned w0 = *(const unsigned*)(p);       // 4B-aligned b32 reads only
        unsigned w1 = *(const unsigned*)(p + 2);
        unsigned w2v = *(const unsigned*)(p + 4);
        float b = bb[k2];
        m6[0] = fmaf(b, bf_lo(w0),  m6[0]);
        m6[1] = fmaf(b, bf_hi(w0),  m6[1]);
        m6[2] = fmaf(b, bf_lo(w1),  m6[2]);
        m6[3] = fmaf(b, bf_hi(w1),  m6[3]);
        m6[4] = fmaf(b, bf_lo(w2v), m6[4]);
        m6[5] = fmaf(b, bf_hi(w2v), m6[5]);
      }
      float part = 0.f;
      #pragma unroll
      for (int jj = 0; jj < 6; ++jj) {
        float vl = (m6[jj] > 0.f) ? m6[jj] : 0.2f*m6[jj];
        part = fmaf(vl, att_j[jj], part);
      }
      part += __shfl_xor(part, 1);
      part += __shfl_xor(part, 2);
      part += __shfl_xor(part, 4);
      aout[s] = part;                       // all lanes of head g hold alpha[s][g]
    }
    #pragma unroll
    for (int s = 0; s < 8; ++s) {
      if ((lane & 7) == s && (base + s) < Ecnt)
        alphaE[(size_t)(base + s)*8 + (lane >> 3)] = aout[s];
    }
  }
}

// ---------- phase A': self-loop alpha (node-parallel, mb @ W2) ----------
__global__ __launch_bounds__(256) void alpha_self_k(
    const float* __restrict__ xl, const float* __restrict__ xr,
    const int* __restrict__ rowptr, const unsigned short* __restrict__ mbbf,
    const float* __restrict__ W2f, const float* __restrict__ bias2_l,
    const float* __restrict__ att_l,
    float* __restrict__ alphaL, int Nn) {
  __shared__ unsigned short W2R[48 * DMv];
  int tid = threadIdx.x;
  for (int i = tid; i < 48*DMv; i += 256) W2R[i] = f2bf(W2f[i]);
  __syncthreads();
  int lane = tid & 63, wv = tid >> 6;
  int j0 = lane * 6;
  float att_j[6], b2[6];
  #pragma unroll
  for (int jj = 0; jj < 6; ++jj) {
    att_j[jj] = att_l[j0 + jj];
    b2[jj]    = bias2_l[j0 + jj];
  }
  int wgid = blockIdx.x*4 + wv;
  for (int it = 0; it < 8; ++it) {
    int t = wgid*8 + it;
    if (t >= Nn) break;
    int deg = rowptr[t+1] - rowptr[t];
    const float* xp = xl + (size_t)t*DMv + j0;
    const float* yp = xr + (size_t)t*DMv + j0;
    float2 a0 = ((const float2*)xp)[0], a1 = ((const float2*)xp)[1], a2 = ((const float2*)xp)[2];
    float2 c0 = ((const float2*)yp)[0], c1 = ((const float2*)yp)[1], c2 = ((const float2*)yp)[2];
    float m6[6];
    m6[0]=a0.x+c0.x; m6[1]=a0.y+c0.y; m6[2]=a1.x+c1.x;
    m6[3]=a1.y+c1.y; m6[4]=a2.x+c2.x; m6[5]=a2.y+c2.y;
    if (deg > 0) {
      #pragma unroll
      for (int jj = 0; jj < 6; ++jj) m6[jj] += b2[jj];
    }
    const uint4* mbp = (const uint4*)(mbbf + (size_t)t*48);
    #pragma unroll
    for (int w = 0; w < 6; ++w) {
      uint4 bu = mbp[w];                    // same addr all lanes -> broadcast
      float bb[8] = {bf_lo(bu.x), bf_hi(bu.x), bf_lo(bu.y), bf_hi(bu.y),
                     bf_lo(bu.z), bf_hi(bu.z), bf_lo(bu.w), bf_hi(bu.w)};
      const unsigned short* wrow = W2R + (w*8)*DMv + j0;
      #pragma unroll
      for (int k2 = 0; k2 < 8; ++k2) {
        const unsigned short* p = wrow + k2*DMv;
        unsigned w0 = *(const unsigned*)(p);
        unsigned w1 = *(const unsigned*)(p + 2);
        unsigned w2v = *(const unsigned*)(p + 4);
        float b = bb[k2];
        m6[0] = fmaf(b, bf_lo(w0),  m6[0]);
        m6[1] = fmaf(b, bf_hi(w0),  m6[1]);
        m6[2] = fmaf(b, bf_lo(w1),  m6[2]);
        m6[3] = fmaf(b, bf_hi(w1),  m6[3]);
        m6[4] = fmaf(b, bf_lo(w2v), m6[4]);
        m6[5] = fmaf(b, bf_hi(w2v), m6[5]);
      }
    }
    float part = 0.f;
    #pragma unroll
    for (int jj = 0; jj < 6; ++jj) {
      float vl = (m6[jj] > 0.f) ? m6[jj] : 0.2f*m6[jj];
      part = fmaf(vl, att_j[jj], part);
    }
    part += __shfl_xor(part, 1);
    part += __shfl_xor(part, 2);
    part += __shfl_xor(part, 4);
    if ((lane & 7) == 0) alphaL[(size_t)t*8 + (lane >> 3)] = part;
  }
}

// ---------- phase B: per-node softmax + aggregation + residual + LN (no LDS) ----------
__global__ __launch_bounds__(256) void agg_k(
    const float* __restrict__ xl, const float* __restrict__ hres,
    const float* __restrict__ alphaE, const float* __restrict__ alphaL,
    const int* __restrict__ rowptr, const int* __restrict__ srcc,
    const float* __restrict__ ln_g, const float* __restrict__ ln_b,
    unsigned short* __restrict__ hbf, int Nn) {
  int tid = threadIdx.x, lane = tid & 63, wv = tid >> 6;
  int t = blockIdx.x*4 + wv;
  if (t >= Nn) return;
  int rp = rowptr[t], deg = rowptr[t+1] - rp;
  int j0 = lane * 6;
  int hh = lane & 7;        // pass-1 head
  int ii = lane >> 3;       // pass-1 edge-sub
  int g  = lane >> 3;       // pass-2 head (of this lane's 6 cols)
  float aL = alphaL[(size_t)t*8 + hh];
  float M = aL;
  for (int b = 0; b < deg; b += 8) {
    int i = b + ii;
    float a = (i < deg) ? alphaE[(size_t)(rp+i)*8 + hh] : -INFINITY;
    M = fmaxf(M, a);
  }
  M = fmaxf(M, __shfl_xor(M, 8));
  M = fmaxf(M, __shfl_xor(M, 16));
  M = fmaxf(M, __shfl_xor(M, 32));
  // self-loop term counted ONCE (ii==0 lane only) — bug fix vs round 4
  float S = (ii == 0) ? __expf(aL - M) : 0.f;
  for (int b = 0; b < deg; b += 8) {
    int i = b + ii;
    if (i < deg) S += __expf(alphaE[(size_t)(rp+i)*8 + hh] - M);
  }
  S += __shfl_xor(S, 8);
  S += __shfl_xor(S, 16);
  S += __shfl_xor(S, 32);
  float Mg  = __shfl(M, g);
  float Sg  = __shfl(S, g);
  float aLg = __shfl(aL, g);
  float inv = 1.0f / (Sg + 1e-16f);
  float acc[6];
  {
    float wl = __expf(aLg - Mg);
    const float* xt = xl + (size_t)t*DMv + j0;
    float2 a0 = ((const float2*)xt)[0], a1 = ((const float2*)xt)[1], a2 = ((const float2*)xt)[2];
    acc[0]=wl*a0.x; acc[1]=wl*a0.y; acc[2]=wl*a1.x;
    acc[3]=wl*a1.y; acc[4]=wl*a2.x; acc[5]=wl*a2.y;
  }
  for (int b = 0; b < deg; b += 8) {
    int i = b + ii;
    float a = (i < deg) ? (alphaE[(size_t)(rp+i)*8 + hh] - M) : -INFINITY;
    float w = __expf(a);
    #pragma unroll
    for (int s = 0; s < 8; ++s) {
      if (b + s < deg) {
        float ws = __shfl(w, 8*s + g);
        int sr = srcc[rp + b + s];
        const float* xp = xl + (size_t)sr*DMv + j0;
        float2 a0 = ((const float2*)xp)[0], a1 = ((const float2*)xp)[1], a2 = ((const float2*)xp)[2];
        acc[0] = fmaf(ws, a0.x, acc[0]);
        acc[1] = fmaf(ws, a0.y, acc[1]);
        acc[2] = fmaf(ws, a1.x, acc[2]);
        acc[3] = fmaf(ws, a1.y, acc[3]);
        acc[4] = fmaf(ws, a2.x, acc[4]);
        acc[5] = fmaf(ws, a2.y, acc[5]);
      }
    }
  }
  // finalize: /S, residual, LayerNorm, write bf16
  const float* hrp = hres + (size_t)t*DMv + j0;
  float outv[6]; float s1 = 0.f, s2 = 0.f;
  #pragma unroll
  for (int jj = 0; jj < 6; ++jj) {
    float o = fmaf(acc[jj], inv, hrp[jj]);
    outv[jj] = o; s1 += o; s2 += o*o;
  }
  #pragma unroll
  for (int m = 1; m < 64; m <<= 1) {
    s1 += __shfl_xor(s1, m);
    s2 += __shfl_xor(s2, m);
  }
  float mu  = s1 * (1.0f/384.0f);
  float var = s2 * (1.0f/384.0f) - mu*mu;
  float rs  = rsqrtf(var + 1e-5f);
  float o0 = (outv[0]-mu)*rs*ln_g[j0+0] + ln_b[j0+0];
  float o1 = (outv[1]-mu)*rs*ln_g[j0+1] + ln_b[j0+1];
  float o2 = (outv[2]-mu)*rs*ln_g[j0+2] + ln_b[j0+2];
  float o3 = (outv[3]-mu)*rs*ln_g[j0+3] + ln_b[j0+3];
  float o4 = (outv[4]-mu)*rs*ln_g[j0+4] + ln_b[j0+4];
  float o5 = (outv[5]-mu)*rs*ln_g[j0+5] + ln_b[j0+5];
  unsigned* hp = (unsigned*)(hbf + (size_t)t*DMv + j0);
  hp[0] = (unsigned)f2bf(o0) | ((unsigned)f2bf(o1) << 16);
  hp[1] = (unsigned)f2bf(o2) | ((unsigned)f2bf(o3) << 16);
  hp[2] = (unsigned)f2bf(o4) | ((unsigned)f2bf(o5) << 16);
}

// ---------- BatchNorm (training-mode batch stats) on bf16 h ----------
__global__ void bn_reduce_k(const unsigned short* __restrict__ hbf, float* __restrict__ sums, int Nn) {
  int c = threadIdx.x;
  float s = 0.f, s2 = 0.f;
  for (int r = blockIdx.x; r < Nn; r += gridDim.x) {
    float v = bf2f(hbf[(size_t)r*DMv + c]);
    s += v; s2 += v*v;
  }
  atomicAdd(&sums[c], s);
  atomicAdd(&sums[DMv + c], s2);
}
__global__ void bn_params_k(const float* __restrict__ sums,
                            const float* __restrict__ bn_g, const float* __restrict__ bn_b,
                            float* __restrict__ scsh, int Nn) {
  int c = threadIdx.x;
  float mu  = sums[c] / (float)Nn;
  float var = sums[DMv + c] / (float)Nn - mu*mu;
  float rs  = rsqrtf(var + 1e-5f);
  float sc  = bn_g[c] * rs;
  scsh[c] = sc;
  scsh[DMv + c] = bn_b[c] - mu*sc;
}
__global__ void bn_apply_k(const unsigned short* __restrict__ hbf, const float* __restrict__ scsh,
                           float* __restrict__ out) {
  int c = threadIdx.x; int n = blockIdx.x;
  size_t i = (size_t)n*DMv + c;
  out[i] = fmaf(bf2f(hbf[i]), scsh[c], scsh[DMv + c]);
}

extern "C" void kernel_launch(void* const* d_in, const int* in_sizes, int n_in,
                              void* d_out, int out_size, void* d_ws, size_t ws_size,
                              hipStream_t stream) {
  const int Nn   = in_sizes[0];
  const int Ecnt = in_sizes[2];
  const int*   x         = (const int*)d_in[0];
  const int*   eindex    = (const int*)d_in[1];
  const int*   srcs      = eindex;
  const int*   tgts      = eindex + Ecnt;
  const float* edge_attr = (const float*)d_in[2];
  const float* lut       = (const float*)d_in[3];
  const float* We0       = (const float*)d_in[4];
  const float* be0       = (const float*)d_in[5];
  const float* Wl        = (const float*)d_in[6];
  const float* bl_       = (const float*)d_in[7];
  const float* Wr        = (const float*)d_in[8];
  const float* br_       = (const float*)d_in[9];
  const float* We        = (const float*)d_in[10];
  const float* att       = (const float*)d_in[11];
  const float* Wres      = (const float*)d_in[12];
  const float* bias_g    = (const float*)d_in[13];
  const float* ln_g      = (const float*)d_in[14];
  const float* ln_b      = (const float*)d_in[15];
  const float* bn_g      = (const float*)d_in[16];
  const float* bn_b      = (const float*)d_in[17];

  char* ws = (char*)d_ws;
  size_t off = 0;
  auto alloc = [&](size_t b) { size_t o = off; off += (b + 255) & ~(size_t)255; return o; };
  unsigned short* hbf   = (unsigned short*)(ws + alloc((size_t)Nn*DMv*2));
  float* xlB   = (float*)(ws + alloc((size_t)Nn*DMv*4));
  float* xrB   = (float*)(ws + alloc((size_t)Nn*DMv*4));
  float* hresB = (float*)(ws + alloc((size_t)Nn*DMv*4));
  unsigned short* mbbf = (unsigned short*)(ws + alloc((size_t)Nn*48*2));
  uint4* bas8  = (uint4*)(ws + alloc((size_t)Ecnt*16));
  int* ofs     = (int*)(ws + alloc((size_t)Ecnt*4));
  uint4* bas8c = (uint4*)(ws + alloc((size_t)Ecnt*16));
  int* ofsc    = (int*)(ws + alloc((size_t)Ecnt*4));
  int* srcc    = (int*)(ws + alloc((size_t)Ecnt*4));
  int* tgtc    = (int*)(ws + alloc((size_t)Ecnt*4));
  float* alphaE = (float*)(ws + alloc((size_t)Ecnt*8*4));
  float* alphaL = (float*)(ws + alloc((size_t)Nn*8*4));
  float* W2    = (float*)(ws + alloc((size_t)2*48*DMv*4));
  float* bias2 = (float*)(ws + alloc((size_t)2*DMv*4));
  unsigned short* WcatT = (unsigned short*)(ws + alloc((size_t)2*1152*DMv*2));
  int* rowptr  = (int*)(ws + alloc((size_t)(Nn+1)*4));
  int* cnt     = (int*)(ws + alloc((size_t)Nn*4));
  int* fillA   = (int*)(ws + alloc((size_t)Nn*4));
  int* bsum    = (int*)(ws + alloc(1024));
  int* bsumx   = (int*)(ws + alloc(1024));
  float* bnsum = (float*)(ws + alloc(2*DMv*4));
  float* scsh  = (float*)(ws + alloc(2*DMv*4));

  hipMemsetAsync(cnt,   0, (size_t)Nn*4, stream);
  hipMemsetAsync(fillA, 0, (size_t)Nn*4, stream);
  hipMemsetAsync(bnsum, 0, 2*DMv*4, stream);

  embed_k<<<Nn, DMv, 0, stream>>>(x, lut, hbf);
  w2_k<<<dim3(49, 2), DMv, 0, stream>>>(We0, be0, We, W2, bias2);
  wcat_k<<<dim3(1152, 2), DMv, 0, stream>>>(Wl, Wr, Wres, WcatT);
  bas8_k<<<(Ecnt+255)/256, 256, 0, stream>>>(edge_attr, bas8, ofs, Ecnt);
  count_k<<<(Ecnt+255)/256, 256, 0, stream>>>(tgts, cnt, Ecnt);
  int nblk = (Nn + 255)/256;
  scan1_k<<<nblk, 256, 0, stream>>>(cnt, rowptr, bsum, Nn);
  scan2_k<<<1, 256, 0, stream>>>(bsum, bsumx, nblk);
  scan3_k<<<nblk, 256, 0, stream>>>(rowptr, bsumx, Nn, Ecnt);
  fill_k<<<(Ecnt+255)/256, 256, 0, stream>>>(srcs, tgts, rowptr, fillA,
                                             bas8, ofs, srcc, tgtc, bas8c, ofsc, Ecnt);
  mb_k<<<(Nn+3)/4, 256, 0, stream>>>(bas8c, ofsc, rowptr, mbbf, Nn);

  for (int l = 0; l < 2; ++l) {
    mfma_cat_k<<<dim3(9, (Nn+127)/128), 256, 0, stream>>>(
        hbf, WcatT + (size_t)l*1152*DMv,
        bl_ + (size_t)l*DMv, br_ + (size_t)l*DMv, bias_g + (size_t)l*DMv,
        xlB, xrB, hresB, Nn);
    alpha_edge_k<<<(Ecnt+127)/128, 256, 0, stream>>>(
        xlB, xrB, bas8c, ofsc, srcc, tgtc,
        W2 + (size_t)l*48*DMv, bias2 + (size_t)l*DMv, att + (size_t)l*DMv,
        alphaE, Ecnt);
    alpha_self_k<<<(Nn+31)/32, 256, 0, stream>>>(
        xlB, xrB, rowptr, mbbf,
        W2 + (size_t)l*48*DMv, bias2 + (size_t)l*DMv, att + (size_t)l*DMv,
        alphaL, Nn);
    agg_k<<<(Nn+3)/4, 256, 0, stream>>>(
        xlB, hresB, alphaE, alphaL, rowptr, srcc,
        ln_g + (size_t)l*DMv, ln_b + (size_t)l*DMv, hbf, Nn);
  }
  bn_reduce_k<<<200, DMv, 0, stream>>>(hbf, bnsum, Nn);
  bn_params_k<<<1, DMv, 0, stream>>>(bnsum, bn_g, bn_b, scsh, Nn);
  bn_apply_k<<<Nn, DMv, 0, stream>>>(hbf, scsh, (float*)d_out);
}